// Round 2
// baseline (33.673 us; speedup 1.0000x reference)
//
#include <hip/hip_runtime.h>

#define BB 8
#define NN 1024
#define FPB 4
#define CLAMP_V 10.0f
#define UNCL_W 0.5f
#define EPSN 1e-8f

struct F3 { float x, y, z; };

__device__ __forceinline__ F3 ld3(const float* p, int base) {
    F3 r; r.x = p[base]; r.y = p[base + 1]; r.z = p[base + 2]; return r;
}
__device__ __forceinline__ F3 sub3(F3 a, F3 b) {
    F3 r; r.x = a.x - b.x; r.y = a.y - b.y; r.z = a.z - b.z; return r;
}
__device__ __forceinline__ F3 cross3(F3 a, F3 b) {
    F3 r;
    r.x = a.y * b.z - a.z * b.y;
    r.y = a.z * b.x - a.x * b.z;
    r.z = a.x * b.y - a.y * b.x;
    return r;
}
__device__ __forceinline__ F3 normv(F3 v) {
    float n = sqrtf(v.x * v.x + v.y * v.y + v.z * v.z) + EPSN;
    float inv = 1.0f / n;
    F3 r; r.x = v.x * inv; r.y = v.y * inv; r.z = v.z * inv; return r;
}

// Kernel 1: per-frame masked partial sums over all j.
// grid = (BB*NN)/FPB blocks, 256 threads. Block handles FPB consecutive frames
// of one batch. d_ws gets BB*NN floats (one partial per frame i).
__global__ __launch_bounds__(256) void fape_partial_kernel(
    const float* __restrict__ n_in, const float* __restrict__ ca_in,
    const float* __restrict__ c_in, const float* __restrict__ pred,
    const float* __restrict__ tru, const int* __restrict__ mask,
    float* __restrict__ partial)
{
    const int blk = blockIdx.x;
    const int b = blk / (NN / FPB);
    const int i0 = (blk % (NN / FPB)) * FPB;
    const int tid = threadIdx.x;

    // Build FPB rotations (columns x,y,z) + translations, redundantly per thread.
    float Rx[FPB][3], Ry[FPB][3], Rz[FPB][3], T[FPB][3];
#pragma unroll
    for (int f = 0; f < FPB; ++f) {
        const int idx = (b * NN + i0 + f) * 3;
        F3 ca = ld3(ca_in, idx);
        F3 nn = ld3(n_in, idx);
        F3 cc = ld3(c_in, idx);
        F3 vcn = normv(sub3(nn, ca));
        F3 x = normv(sub3(cc, ca));
        F3 z = normv(cross3(x, vcn));
        F3 y = normv(cross3(z, x));
        Rx[f][0] = x.x; Rx[f][1] = x.y; Rx[f][2] = x.z;
        Ry[f][0] = y.x; Ry[f][1] = y.y; Ry[f][2] = y.z;
        Rz[f][0] = z.x; Rz[f][1] = z.y; Rz[f][2] = z.z;
        T[f][0] = ca.x; T[f][1] = ca.y; T[f][2] = ca.z;
    }

    float acc[FPB];
#pragma unroll
    for (int f = 0; f < FPB; ++f) acc[f] = 0.0f;

    for (int j = tid; j < NN; j += 256) {
        const int pj = (b * NN + j) * 3;
        F3 p = ld3(pred, pj);
        F3 q = ld3(tru, pj);
        const float mj = mask[b * NN + j] ? 1.0f : 0.0f;
#pragma unroll
        for (int f = 0; f < FPB; ++f) {
            // dp = pred_j - t_i ; dt = true_j - t_i (mirror reference op order)
            float dpx = p.x - T[f][0], dpy = p.y - T[f][1], dpz = p.z - T[f][2];
            float dtx = q.x - T[f][0], dty = q.y - T[f][1], dtz = q.z - T[f][2];
            // local = R^T d : component c = column_c . d
            float lp0 = Rx[f][0] * dpx + Rx[f][1] * dpy + Rx[f][2] * dpz;
            float lp1 = Ry[f][0] * dpx + Ry[f][1] * dpy + Ry[f][2] * dpz;
            float lp2 = Rz[f][0] * dpx + Rz[f][1] * dpy + Rz[f][2] * dpz;
            float lt0 = Rx[f][0] * dtx + Rx[f][1] * dty + Rx[f][2] * dtz;
            float lt1 = Ry[f][0] * dtx + Ry[f][1] * dty + Ry[f][2] * dtz;
            float lt2 = Rz[f][0] * dtx + Rz[f][1] * dty + Rz[f][2] * dtz;
            float d0 = lp0 - lt0, d1 = lp1 - lt1, d2 = lp2 - lt2;
            float diff = sqrtf(d0 * d0 + d1 * d1 + d2 * d2);
            float cl = fminf(diff, CLAMP_V);
            float pp = cl + UNCL_W * (diff - cl);
            acc[f] += pp * mj;
        }
    }

    // Reduce each acc[f] across the block (4 waves of 64).
    const int lane = tid & 63;
    const int wid = tid >> 6;
    __shared__ float smem[4][FPB];
#pragma unroll
    for (int f = 0; f < FPB; ++f) {
        float v = acc[f];
#pragma unroll
        for (int off = 32; off > 0; off >>= 1)
            v += __shfl_down(v, off, 64);
        if (lane == 0) smem[wid][f] = v;
    }
    __syncthreads();
    if (tid < FPB) {
        float s = smem[0][tid] + smem[1][tid] + smem[2][tid] + smem[3][tid];
        const float mi = mask[b * NN + i0 + tid] ? 1.0f : 0.0f;
        partial[blk * FPB + tid] = mi * s;
    }
}

// Kernel 2: reduce BB*NN partials + mask sum -> scalar out.
__global__ __launch_bounds__(256) void fape_final_kernel(
    const float* __restrict__ partial, const int* __restrict__ mask,
    float* __restrict__ out)
{
    const int tid = threadIdx.x;
    float s = 0.0f, ms = 0.0f;
    for (int i = tid; i < BB * NN; i += 256) {
        s += partial[i];
        ms += mask[i] ? 1.0f : 0.0f;
    }
    const int lane = tid & 63;
    const int wid = tid >> 6;
#pragma unroll
    for (int off = 32; off > 0; off >>= 1) {
        s += __shfl_down(s, off, 64);
        ms += __shfl_down(ms, off, 64);
    }
    __shared__ float sm_s[4], sm_m[4];
    if (lane == 0) { sm_s[wid] = s; sm_m[wid] = ms; }
    __syncthreads();
    if (tid == 0) {
        float tot = sm_s[0] + sm_s[1] + sm_s[2] + sm_s[3];
        float mt = sm_m[0] + sm_m[1] + sm_m[2] + sm_m[3];
        out[0] = tot / (mt + 1e-8f);
    }
}

extern "C" void kernel_launch(void* const* d_in, const int* in_sizes, int n_in,
                              void* d_out, int out_size, void* d_ws, size_t ws_size,
                              hipStream_t stream) {
    const float* n_in_p = (const float*)d_in[0];
    const float* ca_p   = (const float*)d_in[1];
    const float* c_p    = (const float*)d_in[2];
    const float* pred_p = (const float*)d_in[3];
    const float* true_p = (const float*)d_in[4];
    const int* mask_p   = (const int*)d_in[5];
    float* out = (float*)d_out;
    float* partial = (float*)d_ws;  // BB*NN floats = 32 KB

    const int nblocks = (BB * NN) / FPB;  // 2048
    fape_partial_kernel<<<nblocks, 256, 0, stream>>>(
        n_in_p, ca_p, c_p, pred_p, true_p, mask_p, partial);
    fape_final_kernel<<<1, 256, 0, stream>>>(partial, mask_p, out);
}

// Round 3
// 12.601 us; speedup vs baseline: 2.6723x; 2.6723x over previous
//
#include <hip/hip_runtime.h>

#define BB 8
#define NN 1024
#define CLAMP_V 10.0f
#define UNCL_W 0.5f

// FAPE with orthonormal frames: t_i cancels in (pred_local - true_local) and
// R_i^T preserves norms, so diff(i,j) == ||pred_j - true_j|| independent of i.
//   total = sum_b (sum_i m_i) * (sum_j m_j * g(||pred_j - true_j||))
//   out   = total / (sum m + 1e-8)
// Single block, 1024 threads = 16 waves; 2 waves (128 threads) per batch,
// each thread handles 8 elements. Fully deterministic reduction.
__global__ __launch_bounds__(1024) void fape_fast_kernel(
    const float* __restrict__ pred, const float* __restrict__ tru,
    const int* __restrict__ mask, float* __restrict__ out)
{
    const int tid = threadIdx.x;
    const int b = tid >> 7;   // batch 0..7
    const int l = tid & 127;  // lane-within-batch 0..127

    float gs = 0.0f, ms = 0.0f;
#pragma unroll
    for (int k = 0; k < 8; ++k) {
        const int e = b * NN + l + k * 128;
        const int pe = e * 3;
        float dx = pred[pe]     - tru[pe];
        float dy = pred[pe + 1] - tru[pe + 1];
        float dz = pred[pe + 2] - tru[pe + 2];
        float diff = sqrtf(dx * dx + dy * dy + dz * dz);
        float cl = fminf(diff, CLAMP_V);
        float pp = cl + UNCL_W * (diff - cl);
        float m = mask[e] ? 1.0f : 0.0f;
        gs += pp * m;
        ms += m;
    }

    // Wave-level reduce (64 lanes).
#pragma unroll
    for (int off = 32; off > 0; off >>= 1) {
        gs += __shfl_down(gs, off, 64);
        ms += __shfl_down(ms, off, 64);
    }

    __shared__ float sg[16], sm[16];
    __shared__ float prod[8], msb[8];
    const int wid = tid >> 6;  // 16 waves; waves 2b, 2b+1 belong to batch b
    if ((tid & 63) == 0) { sg[wid] = gs; sm[wid] = ms; }
    __syncthreads();

    if (tid < 8) {
        float Sg = sg[2 * tid] + sg[2 * tid + 1];  // sum_j m_j g_j  (batch tid)
        float Sm = sm[2 * tid] + sm[2 * tid + 1];  // sum_i m_i      (batch tid)
        prod[tid] = Sg * Sm;
        msb[tid] = Sm;
    }
    __syncthreads();

    if (tid == 0) {
        float tot = 0.0f, mt = 0.0f;
#pragma unroll
        for (int i = 0; i < 8; ++i) { tot += prod[i]; mt += msb[i]; }
        out[0] = tot / (mt + 1e-8f);
    }
}

extern "C" void kernel_launch(void* const* d_in, const int* in_sizes, int n_in,
                              void* d_out, int out_size, void* d_ws, size_t ws_size,
                              hipStream_t stream) {
    // inputs: n, ca, c, pred_pos, true_pos, mask — frames are unused (see above).
    const float* pred_p = (const float*)d_in[3];
    const float* true_p = (const float*)d_in[4];
    const int* mask_p   = (const int*)d_in[5];
    float* out = (float*)d_out;

    fape_fast_kernel<<<1, 1024, 0, stream>>>(pred_p, true_p, mask_p, out);
}